// Round 6
// baseline (123.687 us; speedup 1.0000x reference)
//
#include <hip/hip_runtime.h>
#include <hip/hip_bf16.h>

#define NROWS 65536
#define DIM   64
#define NE    512
#define BM    64     // rows per block
#define BE    128    // embeds per LDS tile
#define TM    4      // rows per thread
#define TE    8      // embeds per thread
#define NTILES (NE/BE)
#define ZSTR  68     // padded z row stride in floats

// d_out is FLOAT32: [ z_q (4194304) | indices-as-float (65536) | loss (1) ]

#define BETTER(d,i,D,I) ((d) < (D) || ((d) == (D) && (i) < (I)))

// numpy pairwise sum of squares for n=64 contiguous f32 (loops.c.src order):
// r[j]=a[j]; for i=8..56 step 8: r[j]+=a[i+j]; res=((r0+r1)+(r2+r3))+((r4+r5)+(r6+r7))
// __fmul_rn/__fadd_rn forbid FMA contraction (numpy squares then sums).
static __device__ __forceinline__ float np_sumsq64(const float* __restrict__ a) {
    float r[8];
    #pragma unroll
    for (int j = 0; j < 8; ++j) r[j] = __fmul_rn(a[j], a[j]);
    #pragma unroll
    for (int i = 8; i < 64; i += 8)
        #pragma unroll
        for (int j = 0; j < 8; ++j)
            r[j] = __fadd_rn(r[j], __fmul_rn(a[i + j], a[i + j]));
    return __fadd_rn(__fadd_rn(__fadd_rn(r[0], r[1]), __fadd_rn(r[2], r[3])),
                     __fadd_rn(__fadd_rn(r[4], r[5]), __fadd_rn(r[6], r[7])));
}

// K1: per-row argmin replicating numpy f32 semantics at the decision point.
__global__ __launch_bounds__(256) void vq_argmin(
    const float* __restrict__ z, const float* __restrict__ ew,
    float* __restrict__ out, float* __restrict__ part)
{
    __shared__ __align__(16) float zs[BM * ZSTR];   // padded z tile
    __shared__ __align__(16) float es[BE * DIM];    // embed tile; reused as scan
    __shared__ float ynorm[NE];                     // np-pairwise ||e||^2, all 512

    const int tid = threadIdx.x;
    const int tm  = tid >> 4;    // row group
    const int te  = tid & 15;    // embed group
    const int R0  = blockIdx.x * BM;

    {   // stage z tile (coalesced float4 -> padded LDS rows)
        const float4* zg = (const float4*)(z + (size_t)R0 * DIM);
        #pragma unroll
        for (int i = 0; i < 4; ++i) {
            int f4 = tid + 256 * i;
            int r  = f4 >> 4, c4 = f4 & 15;
            *(float4*)(zs + r * ZSTR + c4 * 4) = zg[f4];
        }
    }
    __syncthreads();

    // per-row X = np-pairwise ||z_row||^2 (thread tid owns row tid, kept in reg)
    float xnorm = 0.f;
    if (tid < BM) xnorm = np_sumsq64(zs + tid * ZSTR);

    float d1[TM], d2[TM];
    int   i1[TM], i2[TM];
    #pragma unroll
    for (int mi = 0; mi < TM; ++mi) { d1[mi] = d2[mi] = 3.4e38f; i1[mi] = i2[mi] = 0; }

    for (int t = 0; t < NTILES; ++t) {
        const int e0 = t * BE;
        __syncthreads();
        {
            const float4* eg = (const float4*)(ew + (size_t)e0 * DIM);
            float4* el = (float4*)es;
            #pragma unroll
            for (int i = 0; i < 8; ++i) el[tid + 256 * i] = eg[tid + 256 * i];
        }
        __syncthreads();
        if (tid < BE) ynorm[e0 + tid] = np_sumsq64(es + tid * DIM);
        __syncthreads();

        float acc[TM][TE];
        #pragma unroll
        for (int mi = 0; mi < TM; ++mi)
            #pragma unroll
            for (int ei = 0; ei < TE; ++ei) acc[mi][ei] = 0.f;

        for (int kq = 0; kq < 16; ++kq) {
            const int u = (kq + te) & 15;
            float4 zf[TM], ef[TE];
            #pragma unroll
            for (int mi = 0; mi < TM; ++mi)
                zf[mi] = *(const float4*)(zs + (tm * TM + mi) * ZSTR + 4 * u);
            #pragma unroll
            for (int ei = 0; ei < TE; ++ei)
                ef[ei] = *(const float4*)(es + (te * TE + ei) * DIM + 4 * u);
            #pragma unroll
            for (int mi = 0; mi < TM; ++mi)
                #pragma unroll
                for (int ei = 0; ei < TE; ++ei) {
                    acc[mi][ei] = fmaf(zf[mi].x, ef[ei].x, acc[mi][ei]);
                    acc[mi][ei] = fmaf(zf[mi].y, ef[ei].y, acc[mi][ei]);
                    acc[mi][ei] = fmaf(zf[mi].z, ef[ei].z, acc[mi][ei]);
                    acc[mi][ei] = fmaf(zf[mi].w, ef[ei].w, acc[mi][ei]);
                }
        }

        // rank candidates with fine-grained approx d = ||e||^2 - 2 z.e
        #pragma unroll
        for (int mi = 0; mi < TM; ++mi)
            #pragma unroll
            for (int ei = 0; ei < TE; ++ei) {
                int e = e0 + te * TE + ei;
                float d = ynorm[e] - 2.0f * acc[mi][ei];
                if (d < d1[mi]) { d2[mi] = d1[mi]; i2[mi] = i1[mi]; d1[mi] = d; i1[mi] = e; }
                else if (d < d2[mi]) { d2[mi] = d; i2[mi] = e; }
            }
    }

    // deposit per-thread top-2 into LDS (reuse es), merge per row
    __syncthreads();
    float4* scan = (float4*)es;               // [BM][17] padded float4 entries
    #pragma unroll
    for (int mi = 0; mi < TM; ++mi) {
        int row = tm * TM + mi;
        float4 v;
        v.x = d1[mi]; v.y = __int_as_float(i1[mi]);
        v.z = d2[mi]; v.w = __int_as_float(i2[mi]);
        scan[row * 17 + te] = v;
    }
    __syncthreads();

    float rowmin = 0.f;
    if (tid < BM) {
        // ---- per-row top-4 merge (explicit registers, tie -> lower index) ----
        float bd0 = 3.4e38f, bd1f = 3.4e38f, bd2f = 3.4e38f, bd3f = 3.4e38f;
        int   bi0 = 0, bi1 = 0, bi2 = 0, bi3 = 0;
        #pragma unroll
        for (int k = 0; k < 16; ++k) {        // ascending lane order
            float4 v = scan[tid * 17 + k];
            float a = v.x; int ia = __float_as_int(v.y);
            float b = v.z; int ib = __float_as_int(v.w);
            if (BETTER(a, ia, bd0, bi0)) {
                bd3f = bd2f; bi3 = bi2; bd2f = bd1f; bi2 = bi1;
                bd1f = bd0;  bi1 = bi0; bd0 = a; bi0 = ia;
            } else if (BETTER(a, ia, bd1f, bi1)) {
                bd3f = bd2f; bi3 = bi2; bd2f = bd1f; bi2 = bi1; bd1f = a; bi1 = ia;
            } else if (BETTER(a, ia, bd2f, bi2)) {
                bd3f = bd2f; bi3 = bi2; bd2f = a; bi2 = ia;
            } else if (BETTER(a, ia, bd3f, bi3)) {
                bd3f = a; bi3 = ia;
            }
            if (BETTER(b, ib, bd0, bi0)) {
                bd3f = bd2f; bi3 = bi2; bd2f = bd1f; bi2 = bi1;
                bd1f = bd0;  bi1 = bi0; bd0 = b; bi0 = ib;
            } else if (BETTER(b, ib, bd1f, bi1)) {
                bd3f = bd2f; bi3 = bi2; bd2f = bd1f; bi2 = bi1; bd1f = b; bi1 = ib;
            } else if (BETTER(b, ib, bd2f, bi2)) {
                bd3f = bd2f; bi3 = bi2; bd2f = b; bi2 = ib;
            } else if (BETTER(b, ib, bd3f, bi3)) {
                bd3f = b; bi3 = ib;
            }
        }

        // ---- np-f32 re-rank of the 4 candidates ----
        // d_np = fl32( fl32(X + Y) - 2*fl32(dot) ), dot = correctly-rounded f64
        const float* zr = zs + tid * ZSTR;
        float  bestd = 3.4e38f;
        int    win   = -1;
        int cand[4] = { bi0, bi1, bi2, bi3 };
        #pragma unroll
        for (int c = 0; c < 4; ++c) {
            int ic = cand[c] & (NE - 1);
            const float* ec = ew + (size_t)ic * DIM;
            double m64 = 0.0;
            #pragma unroll
            for (int j = 0; j < 64; ++j)
                m64 = fma((double)zr[j], (double)ec[j], m64);
            float W = __fadd_rn(xnorm, ynorm[ic]);
            float Z = 2.0f * (float)m64;          // exact *2
            float d = __fadd_rn(W, -Z);           // fl32(W - Z)
            if (win < 0 || BETTER(d, ic, bestd, win)) { bestd = d; win = ic; }
        }

        // exact f64 ||z - e_win||^2 for the loss
        const float* ecw = ew + (size_t)win * DIM;
        double dd = 0.0;
        #pragma unroll
        for (int j = 0; j < 64; ++j) {
            double x = (double)zr[j] - (double)ecw[j];
            dd += x * x;
        }
        rowmin = (float)dd;
        out[(size_t)NROWS * DIM + R0 + tid] = (float)win;   // f32 index, exact
    }

    // wave-0 reduce of min distances -> part[bid]
    if (tid < 64) {
        float s = rowmin;
        #pragma unroll
        for (int off = 32; off >= 1; off >>= 1) s += __shfl_xor(s, off, 64);
        if (tid == 0) part[blockIdx.x] = s;
    }
}

// K2: stream-ordered after K1. Reads this block's f32 indices, gathers ew
// (L2-hot, 128 KB), writes the z_q chunk as float32.
__global__ __launch_bounds__(256) void vq_write(
    const float* __restrict__ ew, float* __restrict__ out)
{
    __shared__ int ridx[BM];
    const int tid = threadIdx.x;
    const int R0  = blockIdx.x * BM;
    if (tid < BM)
        ridx[tid] = ((int)out[(size_t)NROWS * DIM + R0 + tid]) & (NE - 1);
    __syncthreads();
    #pragma unroll
    for (int i = 0; i < 4; ++i) {
        int f4  = tid + 256 * i;
        int row = f4 >> 4;
        int c4  = f4 & 15;
        int idx = ridx[row];
        float4 v = *(const float4*)(ew + (size_t)idx * DIM + c4 * 4);
        *(float4*)(out + (size_t)R0 * DIM + (size_t)f4 * 4) = v;
    }
}

// K3: fp64 sum of per-block partials -> commitment loss slot (f32).
__global__ __launch_bounds__(256) void vq_loss(
    const float* __restrict__ part, float* __restrict__ out)
{
    __shared__ double ws[4];
    int tid = threadIdx.x;
    double s = 0.0;
    #pragma unroll
    for (int i = 0; i < 4; ++i) s += (double)part[tid + 256 * i];
    #pragma unroll
    for (int off = 32; off >= 1; off >>= 1) s += __shfl_xor(s, off, 64);
    if ((tid & 63) == 0) ws[tid >> 6] = s;
    __syncthreads();
    if (tid == 0) {
        out[(size_t)NROWS * DIM + NROWS] =
            (float)(0.25 * (ws[0] + ws[1] + ws[2] + ws[3])
                    / (double)((size_t)NROWS * DIM));
    }
}

extern "C" void kernel_launch(void* const* d_in, const int* in_sizes, int n_in,
                              void* d_out, int out_size, void* d_ws, size_t ws_size,
                              hipStream_t stream) {
    const float* z  = (const float*)d_in[0];
    const float* ew = (const float*)d_in[1];
    float* out  = (float*)d_out;
    float* part = (float*)d_ws;   // 1024 floats, fully overwritten every call
    vq_argmin<<<NROWS / BM, 256, 0, stream>>>(z, ew, out, part);
    vq_write<<<NROWS / BM, 256, 0, stream>>>(ew, out);
    vq_loss<<<1, 256, 0, stream>>>(part, out);
}

// Round 7
// 57.157 us; speedup vs baseline: 2.1640x; 2.1640x over previous
//
#include <hip/hip_runtime.h>

#define NROWS 65536
#define DIM   64
#define NE    512
#define RPB   256     // k1 rows per block (4 waves x 64 rows)
#define BM2   64      // k2 rows per block

// d_out is FLOAT32: [ z_q (4194304) | indices-as-float (65536) | loss (1) ]

typedef __attribute__((ext_vector_type(8)))  short bf16x8;
typedef __attribute__((ext_vector_type(16))) float f32x16;

static __device__ __forceinline__ unsigned short bf16rne(float x) {
    unsigned int u = __float_as_uint(x);
    u += 0x7FFFu + ((u >> 16) & 1u);            // RNE (finite inputs only)
    return (unsigned short)(u >> 16);
}
static __device__ __forceinline__ float bf16tof(unsigned short h) {
    return __uint_as_float(((unsigned int)h) << 16);
}

// K1: split-bf16 MFMA distance core (D = E * Z^T so per-z-row distances are
// lane-local), top-2 pool per half-lane, np-f32 re-rank of pool, wave-parallel
// exact np rescan for near-tie flagged rows. Writes f32 indices + per-block
// exact f64 min-distance sums.
__global__ __launch_bounds__(256) void vq_argmin(
    const float* __restrict__ z, const float* __restrict__ ew,
    float* __restrict__ out, float* __restrict__ part)
{
    __shared__ __align__(16) char  smem[131072];  // ew split-bf16: 512 rows x 256B (eh|el), XOR-swizzled
    __shared__ float ynorm[NE];                   // np-pairwise ||e||^2
    __shared__ float wsum[4];

    const int tid  = threadIdx.x;
    const int lane = tid & 63;
    const int w    = tid >> 6;
    const int hh   = lane >> 5;     // half-lane
    const int l31  = lane & 31;
    const int R0   = blockIdx.x * RPB;

    // ---- this wave's 64 z rows -> split-bf16 B-fragments (registers) ----
    // B layout (32x32x16): n = lane&31, k = 8*(lane>>5) + j
    bf16x8 zh[2][4], zl[2][4];
    #pragma unroll
    for (int s = 0; s < 2; ++s) {
        const float* zp = z + (size_t)(R0 + w*64 + s*32 + l31) * DIM + hh*8;
        #pragma unroll
        for (int kt = 0; kt < 4; ++kt) {
            float4 p0 = *(const float4*)(zp + kt*16);
            float4 p1 = *(const float4*)(zp + kt*16 + 4);
            float a[8] = {p0.x,p0.y,p0.z,p0.w,p1.x,p1.y,p1.z,p1.w};
            bf16x8 h, l;
            #pragma unroll
            for (int j = 0; j < 8; ++j) {
                unsigned short hb = bf16rne(a[j]);
                h[j] = (short)hb;
                l[j] = (short)bf16rne(a[j] - bf16tof(hb));
            }
            zh[s][kt] = h; zl[s][kt] = l;
        }
    }

    // ---- stage ew -> LDS split-bf16 (swizzled) + np-pairwise ||e||^2 ----
    #pragma unroll
    for (int rr = 0; rr < 2; ++rr) {
        int r = tid + rr*256;
        const float* src = ew + (size_t)r * DIM;
        int sw = (r & 7) << 4;
        float acc8[8];
        #pragma unroll
        for (int c = 0; c < 8; ++c) {
            float4 v0 = *(const float4*)(src + c*8);
            float4 v1 = *(const float4*)(src + c*8 + 4);
            float a[8] = {v0.x,v0.y,v0.z,v0.w,v1.x,v1.y,v1.z,v1.w};
            bf16x8 h, l;
            #pragma unroll
            for (int j = 0; j < 8; ++j) {
                unsigned short hb = bf16rne(a[j]);
                h[j] = (short)hb;
                l[j] = (short)bf16rne(a[j] - bf16tof(hb));
                float sq = __fmul_rn(a[j], a[j]);
                acc8[j] = (c == 0) ? sq : __fadd_rn(acc8[j], sq);
            }
            int off = r*256 + ((c*16) ^ sw);
            *(bf16x8*)(smem + off)       = h;
            *(bf16x8*)(smem + off + 128) = l;
        }
        ynorm[r] = __fadd_rn(__fadd_rn(__fadd_rn(acc8[0],acc8[1]),
                                       __fadd_rn(acc8[2],acc8[3])),
                             __fadd_rn(__fadd_rn(acc8[4],acc8[5]),
                                       __fadd_rn(acc8[6],acc8[7])));
    }
    __syncthreads();

    // ---- main loop: 16 embed tiles of 32; 24 MFMA + fold per tile ----
    float d1a = 3.4e38f, d2a = 3.4e38f, d1b = 3.4e38f, d2b = 3.4e38f;
    int   i1a = 0, i1b = 0;

    for (int t = 0; t < 16; ++t) {
        const int e0 = t * 32;
        f32x16 acc0, acc1;
        #pragma unroll
        for (int g = 0; g < 16; ++g) { acc0[g] = 0.f; acc1[g] = 0.f; }
        const int  arow  = e0 + l31;               // A layout: row = lane&31
        const char* abase = smem + arow*256;
        const int  sw    = (arow & 7) << 4;
        #pragma unroll
        for (int kt = 0; kt < 4; ++kt) {
            const int kb = (kt*32 + hh*16) ^ sw;   // k = 8*(lane>>5)+j
            bf16x8 ah = *(const bf16x8*)(abase + kb);
            bf16x8 al = *(const bf16x8*)(abase + kb + 128);
            acc0 = __builtin_amdgcn_mfma_f32_32x32x16_bf16(ah, zh[0][kt], acc0, 0,0,0);
            acc1 = __builtin_amdgcn_mfma_f32_32x32x16_bf16(ah, zh[1][kt], acc1, 0,0,0);
            acc0 = __builtin_amdgcn_mfma_f32_32x32x16_bf16(ah, zl[0][kt], acc0, 0,0,0);
            acc1 = __builtin_amdgcn_mfma_f32_32x32x16_bf16(ah, zl[1][kt], acc1, 0,0,0);
            acc0 = __builtin_amdgcn_mfma_f32_32x32x16_bf16(al, zh[0][kt], acc0, 0,0,0);
            acc1 = __builtin_amdgcn_mfma_f32_32x32x16_bf16(al, zh[1][kt], acc1, 0,0,0);
        }
        // fold: d = ynorm[e] - 2*dot ; track (d1,i1,d2-value) per set
        #pragma unroll
        for (int g = 0; g < 16; ++g) {
            const int e = e0 + (g & 3) + 8*(g >> 2) + 4*hh;  // C/D row map
            const float yv = ynorm[e];
            {
                float d = fmaf(-2.0f, acc0[g], yv);
                d2a = fminf(fmaxf(d, d1a), d2a);
                bool b = d < d1a;
                i1a = b ? e : i1a;
                d1a = fminf(d, d1a);
            }
            {
                float d = fmaf(-2.0f, acc1[g], yv);
                d2b = fminf(fmaxf(d, d1b), d2b);
                bool b = d < d1b;
                i1b = b ? e : i1b;
                d1b = fminf(d, d1b);
            }
        }
    }

    // ---- exchange pools via LDS (overlay on dead ew region) ----
    __syncthreads();                       // all waves done reading smem
    float4* cand = (float4*)smem;          // [RPB][2] float4 = 8 KB
    {
        int rb0 = w*64 + l31;
        cand[rb0*2 + hh]        = make_float4(d1a, __int_as_float(i1a), d2a, 0.f);
        cand[(rb0+32)*2 + hh]   = make_float4(d1b, __int_as_float(i1b), d2b, 0.f);
    }
    __syncthreads();

    // ---- epilogue: thread tid owns row R0+tid ----
    float zr[64];
    {
        const float* zp2 = z + (size_t)(R0 + tid) * DIM;
        #pragma unroll
        for (int c = 0; c < 16; ++c) {
            float4 v = *(const float4*)(zp2 + c*4);
            zr[c*4+0]=v.x; zr[c*4+1]=v.y; zr[c*4+2]=v.z; zr[c*4+3]=v.w;
        }
    }
    // np-pairwise ||z||^2
    float acc8[8];
    #pragma unroll
    for (int j = 0; j < 8; ++j) acc8[j] = __fmul_rn(zr[j], zr[j]);
    #pragma unroll
    for (int i = 8; i < 64; i += 8)
        #pragma unroll
        for (int j = 0; j < 8; ++j)
            acc8[j] = __fadd_rn(acc8[j], __fmul_rn(zr[i+j], zr[i+j]));
    float xn = __fadd_rn(__fadd_rn(__fadd_rn(acc8[0],acc8[1]),__fadd_rn(acc8[2],acc8[3])),
                         __fadd_rn(__fadd_rn(acc8[4],acc8[5]),__fadd_rn(acc8[6],acc8[7])));

    float4 cA = cand[tid*2 + 0];
    float4 cB = cand[tid*2 + 1];
    int ca = __float_as_int(cA.y) & (NE-1);
    int cb = __float_as_int(cB.y) & (NE-1);

    // np-f32 re-rank of the 2-candidate pool: d = fl32(fl32(X+Y) - 2*fl64dot)
    float bestd = 3.4e38f; int win = -1;
    #pragma unroll
    for (int c = 0; c < 2; ++c) {
        int ic = (c == 0) ? ca : cb;
        const float* ep = ew + (size_t)ic * DIM;
        double m = 0.0;
        #pragma unroll
        for (int q = 0; q < 16; ++q) {
            float4 ev = *(const float4*)(ep + q*4);
            m = fma((double)zr[q*4+0], (double)ev.x, m);
            m = fma((double)zr[q*4+1], (double)ev.y, m);
            m = fma((double)zr[q*4+2], (double)ev.z, m);
            m = fma((double)zr[q*4+3], (double)ev.w, m);
        }
        float W = __fadd_rn(xn, ynorm[ic]);
        float d = __fadd_rn(W, -(2.0f * (float)m));
        if (win < 0 || d < bestd || (d == bestd && ic < win)) { bestd = d; win = ic; }
    }

    // near-tie flag -> wave-parallel exact np rescan (rare: ~0-3 rows/run)
    bool flag = (fminf(cA.z, cB.z) < fminf(cA.x, cB.x) + 3e-5f);
    unsigned long long mb = __ballot(flag);
    while (mb) {
        int fl = __ffsll(mb) - 1;
        mb &= mb - 1;
        float xnf = __shfl(xn, fl, 64);
        const float* zq = z + (size_t)(R0 + w*64 + fl) * DIM;
        float bd = 3.4e38f; int bi = NE;
        for (int k = 0; k < 8; ++k) {
            int e = lane + 64*k;
            const float* ep = ew + (size_t)e * DIM;
            double m = 0.0;
            #pragma unroll
            for (int q = 0; q < 16; ++q) {
                float4 ev = *(const float4*)(ep + q*4);
                float4 zv = *(const float4*)(zq + q*4);
                m = fma((double)zv.x, (double)ev.x, m);
                m = fma((double)zv.y, (double)ev.y, m);
                m = fma((double)zv.z, (double)ev.z, m);
                m = fma((double)zv.w, (double)ev.w, m);
            }
            float W = __fadd_rn(xnf, ynorm[e]);
            float d = __fadd_rn(W, -(2.0f * (float)m));
            if (d < bd || (d == bd && e < bi)) { bd = d; bi = e; }
        }
        #pragma unroll
        for (int off = 32; off >= 1; off >>= 1) {
            float od = __shfl_xor(bd, off, 64);
            int   oi = __shfl_xor(bi, off, 64);
            if (od < bd || (od == bd && oi < bi)) { bd = od; bi = oi; }
        }
        if (lane == fl) win = bi;
    }

    // exact f64 ||z - e_win||^2 for loss; write index
    const float* ewn = ew + (size_t)win * DIM;
    double dd = 0.0;
    #pragma unroll
    for (int q = 0; q < 16; ++q) {
        float4 ev = *(const float4*)(ewn + q*4);
        double x0 = (double)zr[q*4+0] - (double)ev.x;
        double x1 = (double)zr[q*4+1] - (double)ev.y;
        double x2 = (double)zr[q*4+2] - (double)ev.z;
        double x3 = (double)zr[q*4+3] - (double)ev.w;
        dd = fma(x0,x0,dd); dd = fma(x1,x1,dd);
        dd = fma(x2,x2,dd); dd = fma(x3,x3,dd);
    }
    out[(size_t)NROWS*DIM + R0 + tid] = (float)win;

    float s = (float)dd;
    #pragma unroll
    for (int off = 32; off >= 1; off >>= 1) s += __shfl_xor(s, off, 64);
    if (lane == 0) wsum[w] = s;
    __syncthreads();
    if (tid == 0) part[blockIdx.x] = wsum[0]+wsum[1]+wsum[2]+wsum[3];
}

// K2: gather ew by final indices, write z_q chunk (unchanged, proven).
__global__ __launch_bounds__(256) void vq_write(
    const float* __restrict__ ew, float* __restrict__ out)
{
    __shared__ int ridx[BM2];
    const int tid = threadIdx.x;
    const int R0  = blockIdx.x * BM2;
    if (tid < BM2)
        ridx[tid] = ((int)out[(size_t)NROWS * DIM + R0 + tid]) & (NE - 1);
    __syncthreads();
    #pragma unroll
    for (int i = 0; i < 4; ++i) {
        int f4  = tid + 256 * i;
        int row = f4 >> 4;
        int c4  = f4 & 15;
        float4 v = *(const float4*)(ew + (size_t)ridx[row] * DIM + c4 * 4);
        *(float4*)(out + (size_t)R0 * DIM + (size_t)f4 * 4) = v;
    }
}

// K3: f64 sum of 256 per-block partials -> loss slot.
__global__ __launch_bounds__(256) void vq_loss(
    const float* __restrict__ part, float* __restrict__ out)
{
    __shared__ double ws[4];
    int tid = threadIdx.x;
    double s = (double)part[tid];
    #pragma unroll
    for (int off = 32; off >= 1; off >>= 1) s += __shfl_xor(s, off, 64);
    if ((tid & 63) == 0) ws[tid >> 6] = s;
    __syncthreads();
    if (tid == 0)
        out[(size_t)NROWS*DIM + NROWS] =
            (float)(0.25 * (ws[0]+ws[1]+ws[2]+ws[3]) / (double)((size_t)NROWS*DIM));
}

extern "C" void kernel_launch(void* const* d_in, const int* in_sizes, int n_in,
                              void* d_out, int out_size, void* d_ws, size_t ws_size,
                              hipStream_t stream) {
    const float* z  = (const float*)d_in[0];
    const float* ew = (const float*)d_in[1];
    float* out  = (float*)d_out;
    float* part = (float*)d_ws;   // 256 floats, fully overwritten every call
    vq_argmin<<<NROWS / RPB, 256, 0, stream>>>(z, ew, out, part);
    vq_write<<<NROWS / BM2, 256, 0, stream>>>(ew, out);
    vq_loss<<<1, 256, 0, stream>>>(part, out);
}